// Round 10
// baseline (61.311 us; speedup 1.0000x reference)
//
#include <hip/hip_runtime.h>

typedef unsigned short u16;
typedef __attribute__((ext_vector_type(8))) short bf16x8;
typedef __attribute__((ext_vector_type(4))) float f32x4;

#define NB 64
#define NT 1024
#define NO 128
#define ND 128

__device__ __forceinline__ u16 f2bf(float f) {
    union { float f; unsigned u; } v; v.f = f;
    unsigned r = v.u + 0x7FFFu + ((v.u >> 16) & 1u);
    return (u16)(r >> 16);
}
__device__ __forceinline__ float bf2f(short s) {
    union { unsigned u; float f; } v; v.u = ((unsigned)(u16)s) << 16; return v.f;
}

// load 8 consecutive fp32 and convert to a bf16x8 MFMA fragment
__device__ __forceinline__ bf16x8 frag_from_f32(const float* p) {
    const float4 a = *reinterpret_cast<const float4*>(p);
    const float4 b = *reinterpret_cast<const float4*>(p + 4);
    bf16x8 r;
    r[0] = (short)f2bf(a.x); r[1] = (short)f2bf(a.y);
    r[2] = (short)f2bf(a.z); r[3] = (short)f2bf(a.w);
    r[4] = (short)f2bf(b.x); r[5] = (short)f2bf(b.y);
    r[6] = (short)f2bf(b.z); r[7] = (short)f2bf(b.w);
    return r;
}

// ---------------------------------------------------------------------------
// k_P: fused transpose + P-slice GEMM  (P[b] = attn[b]^T @ tok[b], split-K over 4 slices)
//      + weight prep (spread over all blocks)
//      + msg_oT[b] = (obj[b]@Wmo + bmo)^T computed as a tail on ks==0 blocks.
// 64 KB LDS -> 2 blocks/CU.
__global__ __launch_bounds__(512, 4)
void k_P(const float* __restrict__ attn, const float* __restrict__ tok,
         const float* __restrict__ obj, const float* __restrict__ Wmo,
         const float* __restrict__ bmo, const float* __restrict__ Wmt,
         const float* __restrict__ Wut, const float* __restrict__ Wuo,
         u16* __restrict__ Psl, float* __restrict__ rs_part,
         u16* __restrict__ msg_oT, u16* __restrict__ WmtT,
         u16* __restrict__ WutT, u16* __restrict__ WuoT) {
    __shared__ u16 aT[128 * 128];   // [o][t'] swizzled, 32 KB
    __shared__ u16 dT[128 * 128];   // [d][t'] swizzled, 32 KB
    int b = blockIdx.x >> 2, ks = blockIdx.x & 3;
    int tid = threadIdx.x;

    // ---- weight prep: one element per thread across the grid ----
    {
        int idx = blockIdx.x * 512 + tid;
        if (idx < 16384) {
            int k = idx >> 7, n = idx & 127;
            WmtT[n * 128 + k] = f2bf(Wmt[idx]);
        } else if (idx < 49152) {
            int i2 = idx - 16384; int k = i2 >> 7, n = i2 & 127;   // Wut [256][128]
            WutT[n * 256 + (k ^ ((n & 7) << 3))] = f2bf(Wut[i2]);  // swizzled
        } else if (idx < 81920) {
            int i2 = idx - 49152; int k = i2 >> 7, n = i2 & 127;
            WuoT[n * 256 + k] = f2bf(Wuo[i2]);
        }
    }

    int l = tid & 63, w = tid >> 6;   // 8 waves: o-rows w*16..+15
    int l15 = l & 15, lk = (l >> 4) * 8, rsub = (l >> 4) * 4;
    int ro = w * 16 + l15;
    int og = (tid & 31) * 4;        // 4 consecutive c-rows per thread
    int tg = tid >> 5;              // 0..15 -> 8 t-rows each

    f32x4 acc[8] = {};
    float rsum = 0.f;
#pragma unroll
    for (int c = 0; c < 2; c++) {
        int kb = ks * 256 + c * 128;
        const float* asrc = attn + ((size_t)b * NT + kb) * 128;
        const float* tsrc = tok  + ((size_t)b * NT + kb) * 128;
        if (c) __syncthreads();   // prior chunk's MFMA reads done before overwrite
        // ---- stage: fp32 [128 t][128 c] -> LDS bf16 [c][t'] swizzled ----
#pragma unroll
        for (int half = 0; half < 2; half++) {
            const float* src = half ? tsrc : asrc;
            u16* buf = half ? dT : aT;
            int t0 = tg * 8;
            f32x4 v[8];
#pragma unroll
            for (int i = 0; i < 8; i++)
                v[i] = *reinterpret_cast<const f32x4*>(src + (size_t)(t0 + i) * 128 + og);
            int gr = t0 >> 3;   // 0..15
#pragma unroll
            for (int j = 0; j < 4; j++) {
                int o = og + j;
                bf16x8 pk;
#pragma unroll
                for (int i = 0; i < 8; i++) pk[i] = (short)f2bf(v[i][j]);
                *reinterpret_cast<bf16x8*>(&buf[o * 128 + ((gr ^ (o & 15)) << 3)]) = pk;
            }
        }
        __syncthreads();
        // ---- MFMA: K = 128 for this chunk ----
#pragma unroll
        for (int kk = 0; kk < 4; kk++) {
            int tt = kk * 32 + lk;
            bf16x8 a = *reinterpret_cast<const bf16x8*>(
                &aT[ro * 128 + (((tt >> 3) ^ (ro & 15)) << 3)]);
#pragma unroll
            for (int i = 0; i < 8; i++) rsum += bf2f(a[i]);
#pragma unroll
            for (int ct = 0; ct < 8; ct++) {
                int d = ct * 16 + l15;
                bf16x8 bf = *reinterpret_cast<const bf16x8*>(
                    &dT[d * 128 + (((tt >> 3) ^ (d & 15)) << 3)]);
                acc[ct] = __builtin_amdgcn_mfma_f32_16x16x32_bf16(a, bf, acc[ct], 0, 0, 0);
            }
        }
    }
    rsum += __shfl_xor(rsum, 16, 64);
    rsum += __shfl_xor(rsum, 32, 64);
    if (l < 16) rs_part[((size_t)ks * NB + b) * NO + w * 16 + l15] = rsum;
    u16* pout = Psl + (((size_t)(ks * NB + b)) * NO + w * 16) * ND;
#pragma unroll
    for (int ct = 0; ct < 8; ct++)
#pragma unroll
        for (int r = 0; r < 4; r++)
            pout[(size_t)(rsub + r) * ND + ct * 16 + l15] = f2bf(acc[ct][r]);

    // ---- msg_o tail: only ks==0 blocks; reuse aT (WmoT) and dT (output restage) ----
    if (ks == 0) {
        __syncthreads();
        // stage Wmo^T bf16, XOR-swizzled, into aT
#pragma unroll
        for (int i = 0; i < 32; i++) {
            int idx = i * 512 + tid;
            int k = idx >> 7, n = idx & 127;
            aT[n * 128 + (k ^ ((n & 7) << 3))] = f2bf(Wmo[idx]);
        }
        __syncthreads();
        // msg = obj[b] @ Wmo + bmo  (rows o = w*16..+15, cols n = 0..127)
        f32x4 mc[8] = {};
        const float* xp = obj + ((size_t)b * NO + w * 16 + l15) * 128;
#pragma unroll
        for (int kk = 0; kk < 4; kk++) {
            bf16x8 a = frag_from_f32(xp + kk * 32 + lk);
#pragma unroll
            for (int ct = 0; ct < 8; ct++) {
                int n = ct * 16 + l15;
                bf16x8 bfr = *reinterpret_cast<const bf16x8*>(
                    &aT[n * 128 + ((kk * 32 + lk) ^ ((n & 7) << 3))]);
                mc[ct] = __builtin_amdgcn_mfma_f32_16x16x32_bf16(a, bfr, mc[ct], 0, 0, 0);
            }
        }
        // store swizzled into dT[n][o^swz]
#pragma unroll
        for (int ct = 0; ct < 8; ct++) {
            int n = ct * 16 + l15;
            float bv = bmo[n];
            ushort4 pk;
            pk.x = f2bf(mc[ct][0] + bv);
            pk.y = f2bf(mc[ct][1] + bv);
            pk.z = f2bf(mc[ct][2] + bv);
            pk.w = f2bf(mc[ct][3] + bv);
            int o = w * 16 + rsub;
            *reinterpret_cast<ushort4*>(&dT[n * 128 + (o ^ ((n & 7) << 3))]) = pk;
        }
        __syncthreads();
        // linear coalesced copy dT -> msg_oT[b] (layout preserved, stays swizzled)
        u16* mout = msg_oT + (size_t)b * 16384;
#pragma unroll
        for (int i = 0; i < 4; i++) {
            int idx2 = (i * 512 + tid) * 8;
            *reinterpret_cast<bf16x8*>(mout + idx2) = *reinterpret_cast<const bf16x8*>(&dT[idx2]);
        }
    }
}

// ---------------------------------------------------------------------------
// Obj finalize: P = sum slices; agg = P@Wmt + rowsum*bmt; new_o = LN(obj + relu([obj,agg]@Wuo + buo))
__global__ __launch_bounds__(256, 4)
void k_obj_final(const float* __restrict__ obj, const u16* __restrict__ Psl,
                 const float* __restrict__ rs_part, const u16* __restrict__ WmtT,
                 const float* __restrict__ bmt, const u16* __restrict__ WuoT,
                 const float* __restrict__ buo, const float* __restrict__ g,
                 const float* __restrict__ beta, float* __restrict__ out) {
    __shared__ u16 P_lds[32][136];
    __shared__ u16 agg_lds[32][136];
    __shared__ float rs_lds[32];
    __shared__ float part_s[32][2], part_sq[32][2];
    int bid = blockIdx.x;
    int b = bid >> 2, ot = bid & 3;
    int ob = ot * 32;
    int tid = threadIdx.x;
    {   // slice-sum -> P_lds (bf16), rowsum -> rs_lds
        int row = tid >> 3, c0 = (tid & 7) * 16;
        float sm[16];
#pragma unroll
        for (int i = 0; i < 16; i++) sm[i] = 0.f;
#pragma unroll
        for (int ks = 0; ks < 4; ks++) {
            const u16* p = Psl + (((size_t)(ks * NB + b)) * NO + ob + row) * ND + c0;
            bf16x8 v0 = *reinterpret_cast<const bf16x8*>(p);
            bf16x8 v1 = *reinterpret_cast<const bf16x8*>(p + 8);
#pragma unroll
            for (int i = 0; i < 8; i++) { sm[i] += bf2f(v0[i]); sm[8 + i] += bf2f(v1[i]); }
        }
#pragma unroll
        for (int j = 0; j < 4; j++) {
            ushort4 pk;
            pk.x = f2bf(sm[j * 4 + 0]); pk.y = f2bf(sm[j * 4 + 1]);
            pk.z = f2bf(sm[j * 4 + 2]); pk.w = f2bf(sm[j * 4 + 3]);
            *reinterpret_cast<ushort4*>(&P_lds[row][c0 + j * 4]) = pk;
        }
        if (tid < 32) {
            float r = 0.f;
#pragma unroll
            for (int ks = 0; ks < 4; ks++) r += rs_part[((size_t)ks * NB + b) * NO + ob + tid];
            rs_lds[tid] = r;
        }
    }
    __syncthreads();
    int l = tid & 63, w = tid >> 6;
    int l15 = l & 15, lk = (l >> 4) * 8, rsub = (l >> 4) * 4;
    int wr = (w & 1) * 16, wc = (w >> 1) * 64;
    // agg = P @ Wmt (K=128) + rowsum*bmt
    f32x4 agg[4] = {};
#pragma unroll
    for (int kk = 0; kk < 4; kk++) {
        bf16x8 a = *reinterpret_cast<const bf16x8*>(&P_lds[wr + l15][kk * 32 + lk]);
#pragma unroll
        for (int ct = 0; ct < 4; ct++) {
            bf16x8 bf = *reinterpret_cast<const bf16x8*>(WmtT + (wc + ct * 16 + l15) * 128 + kk * 32 + lk);
            agg[ct] = __builtin_amdgcn_mfma_f32_16x16x32_bf16(a, bf, agg[ct], 0, 0, 0);
        }
    }
#pragma unroll
    for (int ct = 0; ct < 4; ct++) {
        int n = wc + ct * 16 + l15;
        float bb = bmt[n];
#pragma unroll
        for (int r = 0; r < 4; r++) {
            float v = agg[ct][r] + rs_lds[wr + rsub + r] * bb;
            agg_lds[wr + rsub + r][n] = f2bf(v);
        }
    }
    __syncthreads();
    // MLP K=256: [obj, agg] @ WuoT
    f32x4 accm[4] = {};
    const float* objp = obj + ((size_t)(b * NO) + ob + wr + l15) * ND;
#pragma unroll
    for (int kk = 0; kk < 8; kk++) {
        int k0 = kk * 32;
        bf16x8 a = (k0 < 128) ? frag_from_f32(objp + k0 + lk)
                              : *reinterpret_cast<const bf16x8*>(&agg_lds[wr + l15][k0 - 128 + lk]);
#pragma unroll
        for (int ct = 0; ct < 4; ct++) {
            bf16x8 bf = *reinterpret_cast<const bf16x8*>(WuoT + (wc + ct * 16 + l15) * 256 + k0 + lk);
            accm[ct] = __builtin_amdgcn_mfma_f32_16x16x32_bf16(a, bf, accm[ct], 0, 0, 0);
        }
    }
    // residual + relu + LN partials (64 cols per wave)
    const float* objr = obj + ((size_t)(b * NO) + ob) * ND;
    float s[4] = {0.f, 0.f, 0.f, 0.f}, sq[4] = {0.f, 0.f, 0.f, 0.f};
#pragma unroll
    for (int ct = 0; ct < 4; ct++) {
        int n = wc + ct * 16 + l15;
        float bv = buo[n];
#pragma unroll
        for (int r = 0; r < 4; r++) {
            int lr = wr + rsub + r;
            float v = objr[(size_t)lr * ND + n] + fmaxf(accm[ct][r] + bv, 0.f);
            accm[ct][r] = v;
            s[r] += v;
            sq[r] += v * v;
        }
    }
#pragma unroll
    for (int ofs = 1; ofs < 16; ofs <<= 1) {
#pragma unroll
        for (int r = 0; r < 4; r++) {
            s[r]  += __shfl_xor(s[r], ofs, 64);
            sq[r] += __shfl_xor(sq[r], ofs, 64);
        }
    }
    if (l15 < 4) {
        float sv = (l15 == 0) ? s[0] : (l15 == 1) ? s[1] : (l15 == 2) ? s[2] : s[3];
        float qv = (l15 == 0) ? sq[0] : (l15 == 1) ? sq[1] : (l15 == 2) ? sq[2] : sq[3];
        part_s[wr + rsub + l15][w >> 1] = sv;
        part_sq[wr + rsub + l15][w >> 1] = qv;
    }
    __syncthreads();
    float mu[4], rstd[4];
#pragma unroll
    for (int r = 0; r < 4; r++) {
        int lr = wr + rsub + r;
        float st = part_s[lr][0] + part_s[lr][1];
        float qt = part_sq[lr][0] + part_sq[lr][1];
        mu[r] = st * (1.f / 128.f);
        rstd[r] = rsqrtf(qt * (1.f / 128.f) - mu[r] * mu[r] + 1e-5f);
    }
#pragma unroll
    for (int ct = 0; ct < 4; ct++) {
        int n = wc + ct * 16 + l15;
        float gn = g[n], bn = beta[n];
#pragma unroll
        for (int r = 0; r < 4; r++) {
            int lr = wr + rsub + r;
            out[((size_t)(b * NO) + ob + lr) * ND + n] = (accm[ct][r] - mu[r]) * rstd[r] * gn + bn;
        }
    }
}

// ---------------------------------------------------------------------------
// Token side v2: 1024-thread blocks (16 waves/CU = 4/SIMD), grid 256, single pass.
// LDS: msg 32K + wut 64K + agg bounce 64K ([16][16][128], XOR-swizzled) = 160 KB.
__global__ __launch_bounds__(1024, 4)
void k_token_update(const float* __restrict__ tok, const float* __restrict__ attn,
                    const u16* __restrict__ msg_oT, const u16* __restrict__ WutT,
                    const float* __restrict__ bupd, const float* __restrict__ g,
                    const float* __restrict__ beta, float* __restrict__ out) {
    __shared__ u16 msg_lds[16384];      // 32 KB, swizzled layout
    __shared__ u16 wut_lds[32768];      // 64 KB, swizzled layout
    __shared__ u16 aggU[32768];         // 64 KB bounce: [16 waves][16 rows][128], XOR-swizzled
    int i = blockIdx.x;
    int b  = ((i >> 5) << 3) + (i & 7);   // bijective XCD-grouping swizzle
    int bq = (i >> 3) & 3;
    int tid = threadIdx.x;
    {   // stage panels (linear copy; swizzle already baked into global layout)
        const u16* msrc = msg_oT + (size_t)b * 16384;
        int idx = tid * 16;
        *reinterpret_cast<bf16x8*>(&msg_lds[idx])     = *reinterpret_cast<const bf16x8*>(msrc + idx);
        *reinterpret_cast<bf16x8*>(&msg_lds[idx + 8]) = *reinterpret_cast<const bf16x8*>(msrc + idx + 8);
#pragma unroll
        for (int k = 0; k < 4; k++) {
            int idx2 = (k * 1024 + tid) * 8;
            *reinterpret_cast<bf16x8*>(&wut_lds[idx2]) = *reinterpret_cast<const bf16x8*>(WutT + idx2);
        }
    }
    __syncthreads();
    int l = tid & 63, w = tid >> 6;   // 16 waves, wave w: rows bq*256 + w*16 ..
    int l15 = l & 15, lk = (l >> 4) * 8, rsub = (l >> 4) * 4;

    int trow = bq * 256 + w * 16;
    size_t rbase = (size_t)b * NT + trow;
    const float* aF   = attn + (rbase + l15) * NO;
    const float* tokp = tok + (rbase + l15) * ND;

    // ---- hoisted global fragment loads ----
    bf16x8 af[4];
#pragma unroll
    for (int kk = 0; kk < 4; kk++)
        af[kk] = frag_from_f32(aF + kk * 32 + lk);
    bf16x8 am0[4];
#pragma unroll
    for (int kk = 0; kk < 4; kk++)
        am0[kk] = frag_from_f32(tokp + kk * 32 + lk);

    // Phase A: agg = attn @ msg_o (K=128), B from LDS.
    f32x4 acc[8] = {};
#pragma unroll
    for (int kk = 0; kk < 4; kk++) {
#pragma unroll
        for (int ct = 0; ct < 8; ct++) {
            int n = ct * 16 + l15;
            bf16x8 bf = *reinterpret_cast<const bf16x8*>(
                &msg_lds[n * 128 + ((kk * 32 + lk) ^ ((n & 7) << 3))]);
            acc[ct] = __builtin_amdgcn_mfma_f32_16x16x32_bf16(af[kk], bf, acc[ct], 0, 0, 0);
        }
    }
    // Phase B: acc -> wave-local bounce (C layout -> A layout), XOR-swizzled [16][128]
    u16* ab = &aggU[w * 2048];
#pragma unroll
    for (int ct = 0; ct < 8; ct++) {
        int n = ct * 16 + l15;
#pragma unroll
        for (int r = 0; r < 4; r++) {
            int row = rsub + r;
            ab[row * 128 + (n ^ ((row & 7) << 3))] = f2bf(acc[ct][r]);
        }
    }
    asm volatile("s_waitcnt lgkmcnt(0)" ::: "memory");
    __builtin_amdgcn_sched_barrier(0);
    // Phase C: MLP K=256. A: tok frags (preloaded) + agg (bounce); B: wut_lds.
    bf16x8 am[8];
#pragma unroll
    for (int kk = 0; kk < 4; kk++) am[kk] = am0[kk];
#pragma unroll
    for (int kk = 0; kk < 4; kk++)
        am[4 + kk] = *reinterpret_cast<const bf16x8*>(
            &ab[l15 * 128 + ((kk * 32 + lk) ^ ((l15 & 7) << 3))]);
    f32x4 accm[8] = {};
#pragma unroll
    for (int kk = 0; kk < 8; kk++) {
#pragma unroll
        for (int ct = 0; ct < 8; ct++) {
            int n = ct * 16 + l15;
            bf16x8 bf = *reinterpret_cast<const bf16x8*>(
                &wut_lds[n * 256 + ((kk * 32 + lk) ^ ((n & 7) << 3))]);
            accm[ct] = __builtin_amdgcn_mfma_f32_16x16x32_bf16(am[kk], bf, accm[ct], 0, 0, 0);
        }
    }
    // Phase D: residual + bias + relu + per-row partial sums (residual re-read, L2-hot)
    const float* tokr = tok + rbase * ND;
    float s[4] = {0.f, 0.f, 0.f, 0.f}, sq[4] = {0.f, 0.f, 0.f, 0.f};
#pragma unroll
    for (int ct = 0; ct < 8; ct++) {
        int n = ct * 16 + l15;
        float bv = bupd[n];
#pragma unroll
        for (int r = 0; r < 4; r++) {
            float v = tokr[(size_t)(rsub + r) * ND + n] + fmaxf(accm[ct][r] + bv, 0.f);
            accm[ct][r] = v;
            s[r] += v;
            sq[r] += v * v;
        }
    }
    // Phase E: 16-lane reduce, normalize, write
#pragma unroll
    for (int ofs = 1; ofs < 16; ofs <<= 1) {
#pragma unroll
        for (int r = 0; r < 4; r++) {
            s[r]  += __shfl_xor(s[r], ofs, 64);
            sq[r] += __shfl_xor(sq[r], ofs, 64);
        }
    }
    float mu[4], rstd[4];
#pragma unroll
    for (int r = 0; r < 4; r++) {
        mu[r] = s[r] * (1.f / 128.f);
        rstd[r] = rsqrtf(sq[r] * (1.f / 128.f) - mu[r] * mu[r] + 1e-5f);
    }
#pragma unroll
    for (int ct = 0; ct < 8; ct++) {
        int n = ct * 16 + l15;
        float gn = g[n], bn = beta[n];
#pragma unroll
        for (int r = 0; r < 4; r++)
            out[(rbase + rsub + r) * ND + n] = (accm[ct][r] - mu[r]) * rstd[r] * gn + bn;
    }
}

// ---------------------------------------------------------------------------
extern "C" void kernel_launch(void* const* d_in, const int* in_sizes, int n_in,
                              void* d_out, int out_size, void* d_ws, size_t ws_size,
                              hipStream_t stream) {
    const float* tok  = (const float*)d_in[0];
    const float* obj  = (const float*)d_in[1];
    const float* attn = (const float*)d_in[2];
    const float* Wmo  = (const float*)d_in[3];
    const float* bmo  = (const float*)d_in[4];
    const float* Wmt  = (const float*)d_in[5];
    const float* bmt  = (const float*)d_in[6];
    const float* Wut  = (const float*)d_in[7];
    const float* but  = (const float*)d_in[8];
    const float* Wuo  = (const float*)d_in[9];
    const float* buo  = (const float*)d_in[10];
    const float* gt   = (const float*)d_in[11];
    const float* bt   = (const float*)d_in[12];
    const float* go   = (const float*)d_in[13];
    const float* bo   = (const float*)d_in[14];
    float* out = (float*)d_out;

    u16* ws = (u16*)d_ws;
    u16* msg_oT = ws;                        // 1048576 u16 (swizzled)
    u16* WmtT   = msg_oT + 1048576;          // 16384
    u16* WutT   = WmtT + 16384;              // 32768 (swizzled)
    u16* WuoT   = WutT + 32768;              // 32768
    u16* Psl    = WuoT + 32768;              // 4194304 (bf16 P slices [4][64][128][128])
    float* rs_part = (float*)(Psl + 4194304);// 32768 f32

    k_P<<<dim3(256), dim3(512), 0, stream>>>(attn, tok, obj, Wmo, bmo, Wmt, Wut, Wuo,
                                             Psl, rs_part, msg_oT, WmtT, WutT, WuoT);
    k_token_update<<<dim3(256), dim3(1024), 0, stream>>>(tok, attn, msg_oT, WutT, but, gt, bt, out);
    k_obj_final<<<dim3(256), dim3(256), 0, stream>>>(obj, Psl, rs_part, WmtT, bmt, WuoT, buo, go, bo,
                                                     out + (size_t)NB * NT * ND);
}

// Round 11
// 59.944 us; speedup vs baseline: 1.0228x; 1.0228x over previous
//
#include <hip/hip_runtime.h>

typedef unsigned short u16;
typedef __attribute__((ext_vector_type(8))) short bf16x8;
typedef __attribute__((ext_vector_type(4))) float f32x4;

#define NB 64
#define NT 1024
#define NO 128
#define ND 128

__device__ __forceinline__ u16 f2bf(float f) {
    union { float f; unsigned u; } v; v.f = f;
    unsigned r = v.u + 0x7FFFu + ((v.u >> 16) & 1u);
    return (u16)(r >> 16);
}
__device__ __forceinline__ float bf2f(short s) {
    union { unsigned u; float f; } v; v.u = ((unsigned)(u16)s) << 16; return v.f;
}

// load 8 consecutive fp32 and convert to a bf16x8 MFMA fragment
__device__ __forceinline__ bf16x8 frag_from_f32(const float* p) {
    const float4 a = *reinterpret_cast<const float4*>(p);
    const float4 b = *reinterpret_cast<const float4*>(p + 4);
    bf16x8 r;
    r[0] = (short)f2bf(a.x); r[1] = (short)f2bf(a.y);
    r[2] = (short)f2bf(a.z); r[3] = (short)f2bf(a.w);
    r[4] = (short)f2bf(b.x); r[5] = (short)f2bf(b.y);
    r[6] = (short)f2bf(b.z); r[7] = (short)f2bf(b.w);
    return r;
}

// ---------------------------------------------------------------------------
// k_P: fused transpose + P-slice GEMM  (P[b] = attn[b]^T @ tok[b], split-K over 4 slices)
//      + weight prep (spread over all blocks)
//      + msg_oT[b] = (obj[b]@Wmo + bmo)^T computed as a tail on ks==0 blocks.
// 64 KB LDS -> 2 blocks/CU.
__global__ __launch_bounds__(512, 4)
void k_P(const float* __restrict__ attn, const float* __restrict__ tok,
         const float* __restrict__ obj, const float* __restrict__ Wmo,
         const float* __restrict__ bmo, const float* __restrict__ Wmt,
         const float* __restrict__ Wut, const float* __restrict__ Wuo,
         u16* __restrict__ Psl, float* __restrict__ rs_part,
         u16* __restrict__ msg_oT, u16* __restrict__ WmtT,
         u16* __restrict__ WutT, u16* __restrict__ WuoT) {
    __shared__ u16 aT[128 * 128];   // [o][t'] swizzled, 32 KB
    __shared__ u16 dT[128 * 128];   // [d][t'] swizzled, 32 KB
    int b = blockIdx.x >> 2, ks = blockIdx.x & 3;
    int tid = threadIdx.x;

    // ---- weight prep: one element per thread across the grid ----
    {
        int idx = blockIdx.x * 512 + tid;
        if (idx < 16384) {
            int k = idx >> 7, n = idx & 127;
            WmtT[n * 128 + k] = f2bf(Wmt[idx]);
        } else if (idx < 49152) {
            int i2 = idx - 16384; int k = i2 >> 7, n = i2 & 127;   // Wut [256][128]
            WutT[n * 256 + (k ^ ((n & 7) << 3))] = f2bf(Wut[i2]);  // swizzled
        } else if (idx < 81920) {
            int i2 = idx - 49152; int k = i2 >> 7, n = i2 & 127;
            WuoT[n * 256 + k] = f2bf(Wuo[i2]);
        }
    }

    int l = tid & 63, w = tid >> 6;   // 8 waves: o-rows w*16..+15
    int l15 = l & 15, lk = (l >> 4) * 8, rsub = (l >> 4) * 4;
    int ro = w * 16 + l15;
    int og = (tid & 31) * 4;        // 4 consecutive c-rows per thread
    int tg = tid >> 5;              // 0..15 -> 8 t-rows each

    f32x4 acc[8] = {};
    float rsum = 0.f;
#pragma unroll
    for (int c = 0; c < 2; c++) {
        int kb = ks * 256 + c * 128;
        const float* asrc = attn + ((size_t)b * NT + kb) * 128;
        const float* tsrc = tok  + ((size_t)b * NT + kb) * 128;
        if (c) __syncthreads();   // prior chunk's MFMA reads done before overwrite
        // ---- stage: fp32 [128 t][128 c] -> LDS bf16 [c][t'] swizzled ----
#pragma unroll
        for (int half = 0; half < 2; half++) {
            const float* src = half ? tsrc : asrc;
            u16* buf = half ? dT : aT;
            int t0 = tg * 8;
            f32x4 v[8];
#pragma unroll
            for (int i = 0; i < 8; i++)
                v[i] = *reinterpret_cast<const f32x4*>(src + (size_t)(t0 + i) * 128 + og);
            int gr = t0 >> 3;   // 0..15
#pragma unroll
            for (int j = 0; j < 4; j++) {
                int o = og + j;
                bf16x8 pk;
#pragma unroll
                for (int i = 0; i < 8; i++) pk[i] = (short)f2bf(v[i][j]);
                *reinterpret_cast<bf16x8*>(&buf[o * 128 + ((gr ^ (o & 15)) << 3)]) = pk;
            }
        }
        __syncthreads();
        // ---- MFMA: K = 128 for this chunk ----
#pragma unroll
        for (int kk = 0; kk < 4; kk++) {
            int tt = kk * 32 + lk;
            bf16x8 a = *reinterpret_cast<const bf16x8*>(
                &aT[ro * 128 + (((tt >> 3) ^ (ro & 15)) << 3)]);
#pragma unroll
            for (int i = 0; i < 8; i++) rsum += bf2f(a[i]);
#pragma unroll
            for (int ct = 0; ct < 8; ct++) {
                int d = ct * 16 + l15;
                bf16x8 bf = *reinterpret_cast<const bf16x8*>(
                    &dT[d * 128 + (((tt >> 3) ^ (d & 15)) << 3)]);
                acc[ct] = __builtin_amdgcn_mfma_f32_16x16x32_bf16(a, bf, acc[ct], 0, 0, 0);
            }
        }
    }
    rsum += __shfl_xor(rsum, 16, 64);
    rsum += __shfl_xor(rsum, 32, 64);
    if (l < 16) rs_part[((size_t)ks * NB + b) * NO + w * 16 + l15] = rsum;
    u16* pout = Psl + (((size_t)(ks * NB + b)) * NO + w * 16) * ND;
#pragma unroll
    for (int ct = 0; ct < 8; ct++)
#pragma unroll
        for (int r = 0; r < 4; r++)
            pout[(size_t)(rsub + r) * ND + ct * 16 + l15] = f2bf(acc[ct][r]);

    // ---- msg_o tail: only ks==0 blocks; reuse aT (WmoT) and dT (output restage) ----
    if (ks == 0) {
        __syncthreads();
        // stage Wmo^T bf16, XOR-swizzled, into aT
#pragma unroll
        for (int i = 0; i < 32; i++) {
            int idx = i * 512 + tid;
            int k = idx >> 7, n = idx & 127;
            aT[n * 128 + (k ^ ((n & 7) << 3))] = f2bf(Wmo[idx]);
        }
        __syncthreads();
        // msg = obj[b] @ Wmo + bmo  (rows o = w*16..+15, cols n = 0..127)
        f32x4 mc[8] = {};
        const float* xp = obj + ((size_t)b * NO + w * 16 + l15) * 128;
#pragma unroll
        for (int kk = 0; kk < 4; kk++) {
            bf16x8 a = frag_from_f32(xp + kk * 32 + lk);
#pragma unroll
            for (int ct = 0; ct < 8; ct++) {
                int n = ct * 16 + l15;
                bf16x8 bfr = *reinterpret_cast<const bf16x8*>(
                    &aT[n * 128 + ((kk * 32 + lk) ^ ((n & 7) << 3))]);
                mc[ct] = __builtin_amdgcn_mfma_f32_16x16x32_bf16(a, bfr, mc[ct], 0, 0, 0);
            }
        }
        // store swizzled into dT[n][o^swz]
#pragma unroll
        for (int ct = 0; ct < 8; ct++) {
            int n = ct * 16 + l15;
            float bv = bmo[n];
            ushort4 pk;
            pk.x = f2bf(mc[ct][0] + bv);
            pk.y = f2bf(mc[ct][1] + bv);
            pk.z = f2bf(mc[ct][2] + bv);
            pk.w = f2bf(mc[ct][3] + bv);
            int o = w * 16 + rsub;
            *reinterpret_cast<ushort4*>(&dT[n * 128 + (o ^ ((n & 7) << 3))]) = pk;
        }
        __syncthreads();
        // linear coalesced copy dT -> msg_oT[b] (layout preserved, stays swizzled)
        u16* mout = msg_oT + (size_t)b * 16384;
#pragma unroll
        for (int i = 0; i < 4; i++) {
            int idx2 = (i * 512 + tid) * 8;
            *reinterpret_cast<bf16x8*>(mout + idx2) = *reinterpret_cast<const bf16x8*>(&dT[idx2]);
        }
    }
}

// ---------------------------------------------------------------------------
// Obj finalize: P = sum slices; agg = P@Wmt + rowsum*bmt; new_o = LN(obj + relu([obj,agg]@Wuo + buo))
__global__ __launch_bounds__(256, 4)
void k_obj_final(const float* __restrict__ obj, const u16* __restrict__ Psl,
                 const float* __restrict__ rs_part, const u16* __restrict__ WmtT,
                 const float* __restrict__ bmt, const u16* __restrict__ WuoT,
                 const float* __restrict__ buo, const float* __restrict__ g,
                 const float* __restrict__ beta, float* __restrict__ out) {
    __shared__ u16 P_lds[32][136];
    __shared__ u16 agg_lds[32][136];
    __shared__ float rs_lds[32];
    __shared__ float part_s[32][2], part_sq[32][2];
    int bid = blockIdx.x;
    int b = bid >> 2, ot = bid & 3;
    int ob = ot * 32;
    int tid = threadIdx.x;
    {   // slice-sum -> P_lds (bf16), rowsum -> rs_lds
        int row = tid >> 3, c0 = (tid & 7) * 16;
        float sm[16];
#pragma unroll
        for (int i = 0; i < 16; i++) sm[i] = 0.f;
#pragma unroll
        for (int ks = 0; ks < 4; ks++) {
            const u16* p = Psl + (((size_t)(ks * NB + b)) * NO + ob + row) * ND + c0;
            bf16x8 v0 = *reinterpret_cast<const bf16x8*>(p);
            bf16x8 v1 = *reinterpret_cast<const bf16x8*>(p + 8);
#pragma unroll
            for (int i = 0; i < 8; i++) { sm[i] += bf2f(v0[i]); sm[8 + i] += bf2f(v1[i]); }
        }
#pragma unroll
        for (int j = 0; j < 4; j++) {
            ushort4 pk;
            pk.x = f2bf(sm[j * 4 + 0]); pk.y = f2bf(sm[j * 4 + 1]);
            pk.z = f2bf(sm[j * 4 + 2]); pk.w = f2bf(sm[j * 4 + 3]);
            *reinterpret_cast<ushort4*>(&P_lds[row][c0 + j * 4]) = pk;
        }
        if (tid < 32) {
            float r = 0.f;
#pragma unroll
            for (int ks = 0; ks < 4; ks++) r += rs_part[((size_t)ks * NB + b) * NO + ob + tid];
            rs_lds[tid] = r;
        }
    }
    __syncthreads();
    int l = tid & 63, w = tid >> 6;
    int l15 = l & 15, lk = (l >> 4) * 8, rsub = (l >> 4) * 4;
    int wr = (w & 1) * 16, wc = (w >> 1) * 64;
    // agg = P @ Wmt (K=128) + rowsum*bmt
    f32x4 agg[4] = {};
#pragma unroll
    for (int kk = 0; kk < 4; kk++) {
        bf16x8 a = *reinterpret_cast<const bf16x8*>(&P_lds[wr + l15][kk * 32 + lk]);
#pragma unroll
        for (int ct = 0; ct < 4; ct++) {
            bf16x8 bf = *reinterpret_cast<const bf16x8*>(WmtT + (wc + ct * 16 + l15) * 128 + kk * 32 + lk);
            agg[ct] = __builtin_amdgcn_mfma_f32_16x16x32_bf16(a, bf, agg[ct], 0, 0, 0);
        }
    }
#pragma unroll
    for (int ct = 0; ct < 4; ct++) {
        int n = wc + ct * 16 + l15;
        float bb = bmt[n];
#pragma unroll
        for (int r = 0; r < 4; r++) {
            float v = agg[ct][r] + rs_lds[wr + rsub + r] * bb;
            agg_lds[wr + rsub + r][n] = f2bf(v);
        }
    }
    __syncthreads();
    // MLP K=256: [obj, agg] @ WuoT
    f32x4 accm[4] = {};
    const float* objp = obj + ((size_t)(b * NO) + ob + wr + l15) * ND;
#pragma unroll
    for (int kk = 0; kk < 8; kk++) {
        int k0 = kk * 32;
        bf16x8 a = (k0 < 128) ? frag_from_f32(objp + k0 + lk)
                              : *reinterpret_cast<const bf16x8*>(&agg_lds[wr + l15][k0 - 128 + lk]);
#pragma unroll
        for (int ct = 0; ct < 4; ct++) {
            bf16x8 bf = *reinterpret_cast<const bf16x8*>(WuoT + (wc + ct * 16 + l15) * 256 + k0 + lk);
            accm[ct] = __builtin_amdgcn_mfma_f32_16x16x32_bf16(a, bf, accm[ct], 0, 0, 0);
        }
    }
    // residual + relu + LN partials (64 cols per wave)
    const float* objr = obj + ((size_t)(b * NO) + ob) * ND;
    float s[4] = {0.f, 0.f, 0.f, 0.f}, sq[4] = {0.f, 0.f, 0.f, 0.f};
#pragma unroll
    for (int ct = 0; ct < 4; ct++) {
        int n = wc + ct * 16 + l15;
        float bv = buo[n];
#pragma unroll
        for (int r = 0; r < 4; r++) {
            int lr = wr + rsub + r;
            float v = objr[(size_t)lr * ND + n] + fmaxf(accm[ct][r] + bv, 0.f);
            accm[ct][r] = v;
            s[r] += v;
            sq[r] += v * v;
        }
    }
#pragma unroll
    for (int ofs = 1; ofs < 16; ofs <<= 1) {
#pragma unroll
        for (int r = 0; r < 4; r++) {
            s[r]  += __shfl_xor(s[r], ofs, 64);
            sq[r] += __shfl_xor(sq[r], ofs, 64);
        }
    }
    if (l15 < 4) {
        float sv = (l15 == 0) ? s[0] : (l15 == 1) ? s[1] : (l15 == 2) ? s[2] : s[3];
        float qv = (l15 == 0) ? sq[0] : (l15 == 1) ? sq[1] : (l15 == 2) ? sq[2] : sq[3];
        part_s[wr + rsub + l15][w >> 1] = sv;
        part_sq[wr + rsub + l15][w >> 1] = qv;
    }
    __syncthreads();
    float mu[4], rstd[4];
#pragma unroll
    for (int r = 0; r < 4; r++) {
        int lr = wr + rsub + r;
        float st = part_s[lr][0] + part_s[lr][1];
        float qt = part_sq[lr][0] + part_sq[lr][1];
        mu[r] = st * (1.f / 128.f);
        rstd[r] = rsqrtf(qt * (1.f / 128.f) - mu[r] * mu[r] + 1e-5f);
    }
#pragma unroll
    for (int ct = 0; ct < 4; ct++) {
        int n = wc + ct * 16 + l15;
        float gn = g[n], bn = beta[n];
#pragma unroll
        for (int r = 0; r < 4; r++) {
            int lr = wr + rsub + r;
            out[((size_t)(b * NO) + ob + lr) * ND + n] = (accm[ct][r] - mu[r]) * rstd[r] * gn + bn;
        }
    }
}

// ---------------------------------------------------------------------------
// Token side (R9 structure + cross-pass prefetch): grid 256, 512 thr, XCD swizzle.
// Both passes' attn/tok fragments issued up-front (T14: hide pass-1 HBM latency
// under pass-0 MFMAs). Residual loads hoisted per pass.
__global__ __launch_bounds__(512, 2)
void k_token_update(const float* __restrict__ tok, const float* __restrict__ attn,
                    const u16* __restrict__ msg_oT, const u16* __restrict__ WutT,
                    const float* __restrict__ bupd, const float* __restrict__ g,
                    const float* __restrict__ beta, float* __restrict__ out) {
    __shared__ u16 msg_lds[16384];      // 32 KB, swizzled layout
    __shared__ u16 wut_lds[32768];      // 64 KB, swizzled layout
    __shared__ u16 agg_b[8][16][136];   // per-wave agg bounce, 34 KB
    int i = blockIdx.x;
    int b  = ((i >> 5) << 3) + (i & 7);   // bijective XCD-grouping swizzle
    int bq = (i >> 3) & 3;
    int tid = threadIdx.x;
    {   // stage panels (linear copy; swizzle already baked into global layout)
        const u16* msrc = msg_oT + (size_t)b * 16384;
#pragma unroll
        for (int k = 0; k < 4; k++) {
            int idx = (k * 512 + tid) * 8;
            *reinterpret_cast<bf16x8*>(&msg_lds[idx]) = *reinterpret_cast<const bf16x8*>(msrc + idx);
        }
#pragma unroll
        for (int k = 0; k < 8; k++) {
            int idx = (k * 512 + tid) * 8;
            *reinterpret_cast<bf16x8*>(&wut_lds[idx]) = *reinterpret_cast<const bf16x8*>(WutT + idx);
        }
    }
    __syncthreads();
    int l = tid & 63, w = tid >> 6;   // 8 waves
    int l15 = l & 15, lk = (l >> 4) * 8, rsub = (l >> 4) * 4;

    // ---- issue BOTH passes' fragment loads up front ----
    size_t rb0 = (size_t)b * NT + bq * 256 + w * 16;
    size_t rb1 = rb0 + 128;
    bf16x8 af[2][4], am0[2][4];
#pragma unroll
    for (int p = 0; p < 2; p++) {
        size_t rb = p ? rb1 : rb0;
        const float* aF   = attn + (rb + l15) * NO;
        const float* tokp = tok + (rb + l15) * ND;
#pragma unroll
        for (int kk = 0; kk < 4; kk++) {
            af[p][kk]  = frag_from_f32(aF + kk * 32 + lk);
            am0[p][kk] = frag_from_f32(tokp + kk * 32 + lk);
        }
    }

#pragma unroll
    for (int pass = 0; pass < 2; pass++) {
        size_t rbase = pass ? rb1 : rb0;
        const float* tokr = tok + rbase * ND;

        // hoisted residual loads for this pass
        float resv[8][4];
#pragma unroll
        for (int ct = 0; ct < 8; ct++)
#pragma unroll
            for (int r = 0; r < 4; r++)
                resv[ct][r] = tokr[(size_t)(rsub + r) * ND + ct * 16 + l15];

        // Phase A: agg = attn @ msg_o (K=128), B from LDS.
        f32x4 acc[8] = {};
#pragma unroll
        for (int kk = 0; kk < 4; kk++) {
#pragma unroll
            for (int ct = 0; ct < 8; ct++) {
                int n = ct * 16 + l15;
                bf16x8 bf = *reinterpret_cast<const bf16x8*>(
                    &msg_lds[n * 128 + ((kk * 32 + lk) ^ ((n & 7) << 3))]);
                acc[ct] = __builtin_amdgcn_mfma_f32_16x16x32_bf16(af[pass][kk], bf, acc[ct], 0, 0, 0);
            }
        }
        // Phase B: acc -> wave-local agg bounce (C layout -> A layout)
#pragma unroll
        for (int ct = 0; ct < 8; ct++) {
            int n = ct * 16 + l15;
#pragma unroll
            for (int r = 0; r < 4; r++)
                agg_b[w][rsub + r][n] = f2bf(acc[ct][r]);
        }
        asm volatile("s_waitcnt lgkmcnt(0)" ::: "memory");
        __builtin_amdgcn_sched_barrier(0);
        // Phase C: MLP K=256. A: tok frags (preloaded) + agg (LDS); B: wut_lds.
        bf16x8 am[8];
#pragma unroll
        for (int kk = 0; kk < 4; kk++) am[kk] = am0[pass][kk];
#pragma unroll
        for (int kk = 0; kk < 4; kk++)
            am[4 + kk] = *reinterpret_cast<const bf16x8*>(&agg_b[w][l15][kk * 32 + lk]);
        f32x4 accm[8] = {};
#pragma unroll
        for (int kk = 0; kk < 8; kk++) {
#pragma unroll
            for (int ct = 0; ct < 8; ct++) {
                int n = ct * 16 + l15;
                bf16x8 bf = *reinterpret_cast<const bf16x8*>(
                    &wut_lds[n * 256 + ((kk * 32 + lk) ^ ((n & 7) << 3))]);
                accm[ct] = __builtin_amdgcn_mfma_f32_16x16x32_bf16(am[kk], bf, accm[ct], 0, 0, 0);
            }
        }
        // Phase D: residual + bias + relu + per-row partial sums (preloaded residual)
        float s[4] = {0.f, 0.f, 0.f, 0.f}, sq[4] = {0.f, 0.f, 0.f, 0.f};
#pragma unroll
        for (int ct = 0; ct < 8; ct++) {
            int n = ct * 16 + l15;
            float bv = bupd[n];
#pragma unroll
            for (int r = 0; r < 4; r++) {
                float v = resv[ct][r] + fmaxf(accm[ct][r] + bv, 0.f);
                accm[ct][r] = v;
                s[r] += v;
                sq[r] += v * v;
            }
        }
        // Phase E: 16-lane reduce, normalize, write
#pragma unroll
        for (int ofs = 1; ofs < 16; ofs <<= 1) {
#pragma unroll
            for (int r = 0; r < 4; r++) {
                s[r]  += __shfl_xor(s[r], ofs, 64);
                sq[r] += __shfl_xor(sq[r], ofs, 64);
            }
        }
        float mu[4], rstd[4];
#pragma unroll
        for (int r = 0; r < 4; r++) {
            mu[r] = s[r] * (1.f / 128.f);
            rstd[r] = rsqrtf(sq[r] * (1.f / 128.f) - mu[r] * mu[r] + 1e-5f);
        }
#pragma unroll
        for (int ct = 0; ct < 8; ct++) {
            int n = ct * 16 + l15;
            float gn = g[n], bn = beta[n];
#pragma unroll
            for (int r = 0; r < 4; r++)
                out[(rbase + rsub + r) * ND + n] = (accm[ct][r] - mu[r]) * rstd[r] * gn + bn;
        }
    }
}

// ---------------------------------------------------------------------------
extern "C" void kernel_launch(void* const* d_in, const int* in_sizes, int n_in,
                              void* d_out, int out_size, void* d_ws, size_t ws_size,
                              hipStream_t stream) {
    const float* tok  = (const float*)d_in[0];
    const float* obj  = (const float*)d_in[1];
    const float* attn = (const float*)d_in[2];
    const float* Wmo  = (const float*)d_in[3];
    const float* bmo  = (const float*)d_in[4];
    const float* Wmt  = (const float*)d_in[5];
    const float* bmt  = (const float*)d_in[6];
    const float* Wut  = (const float*)d_in[7];
    const float* but  = (const float*)d_in[8];
    const float* Wuo  = (const float*)d_in[9];
    const float* buo  = (const float*)d_in[10];
    const float* gt   = (const float*)d_in[11];
    const float* bt   = (const float*)d_in[12];
    const float* go   = (const float*)d_in[13];
    const float* bo   = (const float*)d_in[14];
    float* out = (float*)d_out;

    u16* ws = (u16*)d_ws;
    u16* msg_oT = ws;                        // 1048576 u16 (swizzled)
    u16* WmtT   = msg_oT + 1048576;          // 16384
    u16* WutT   = WmtT + 16384;              // 32768 (swizzled)
    u16* WuoT   = WutT + 32768;              // 32768
    u16* Psl    = WuoT + 32768;              // 4194304 (bf16 P slices [4][64][128][128])
    float* rs_part = (float*)(Psl + 4194304);// 32768 f32

    k_P<<<dim3(256), dim3(512), 0, stream>>>(attn, tok, obj, Wmo, bmo, Wmt, Wut, Wuo,
                                             Psl, rs_part, msg_oT, WmtT, WutT, WuoT);
    k_token_update<<<dim3(256), dim3(512), 0, stream>>>(tok, attn, msg_oT, WutT, but, gt, bt, out);
    k_obj_final<<<dim3(256), dim3(256), 0, stream>>>(obj, Psl, rs_part, WmtT, bmt, WuoT, buo, go, bo,
                                                     out + (size_t)NB * NT * ND);
}

// Round 12
// 55.612 us; speedup vs baseline: 1.1025x; 1.0779x over previous
//
#include <hip/hip_runtime.h>

typedef unsigned short u16;
typedef __attribute__((ext_vector_type(8))) short bf16x8;
typedef __attribute__((ext_vector_type(4))) float f32x4;

#define NB 64
#define NT 1024
#define NO 128
#define ND 128

__device__ __forceinline__ u16 f2bf(float f) {
    union { float f; unsigned u; } v; v.f = f;
    unsigned r = v.u + 0x7FFFu + ((v.u >> 16) & 1u);
    return (u16)(r >> 16);
}
__device__ __forceinline__ float bf2f(short s) {
    union { unsigned u; float f; } v; v.u = ((unsigned)(u16)s) << 16; return v.f;
}

// load 8 consecutive fp32 and convert to a bf16x8 MFMA fragment
__device__ __forceinline__ bf16x8 frag_from_f32(const float* p) {
    const float4 a = *reinterpret_cast<const float4*>(p);
    const float4 b = *reinterpret_cast<const float4*>(p + 4);
    bf16x8 r;
    r[0] = (short)f2bf(a.x); r[1] = (short)f2bf(a.y);
    r[2] = (short)f2bf(a.z); r[3] = (short)f2bf(a.w);
    r[4] = (short)f2bf(b.x); r[5] = (short)f2bf(b.y);
    r[6] = (short)f2bf(b.z); r[7] = (short)f2bf(b.w);
    return r;
}

// ---------------------------------------------------------------------------
// k_P: fused transpose + P-slice GEMM  (P[b] = attn[b]^T @ tok[b], split-K over 4 slices)
//      + weight prep (spread over all blocks)
//      + msg_oT[b] = (obj[b]@Wmo + bmo)^T computed as a tail on ks==0 blocks.
// 64 KB LDS -> 2 blocks/CU.
__global__ __launch_bounds__(512, 4)
void k_P(const float* __restrict__ attn, const float* __restrict__ tok,
         const float* __restrict__ obj, const float* __restrict__ Wmo,
         const float* __restrict__ bmo, const float* __restrict__ Wmt,
         const float* __restrict__ Wut, const float* __restrict__ Wuo,
         u16* __restrict__ Psl, float* __restrict__ rs_part,
         u16* __restrict__ msg_oT, u16* __restrict__ WmtT,
         u16* __restrict__ WutT, u16* __restrict__ WuoT) {
    __shared__ u16 aT[128 * 128];   // [o][t'] swizzled, 32 KB
    __shared__ u16 dT[128 * 128];   // [d][t'] swizzled, 32 KB
    int b = blockIdx.x >> 2, ks = blockIdx.x & 3;
    int tid = threadIdx.x;

    // ---- weight prep: one element per thread across the grid ----
    {
        int idx = blockIdx.x * 512 + tid;
        if (idx < 16384) {
            int k = idx >> 7, n = idx & 127;
            WmtT[n * 128 + k] = f2bf(Wmt[idx]);
        } else if (idx < 49152) {
            int i2 = idx - 16384; int k = i2 >> 7, n = i2 & 127;   // Wut [256][128]
            WutT[n * 256 + (k ^ ((n & 7) << 3))] = f2bf(Wut[i2]);  // swizzled
        } else if (idx < 81920) {
            int i2 = idx - 49152; int k = i2 >> 7, n = i2 & 127;
            WuoT[n * 256 + k] = f2bf(Wuo[i2]);
        }
    }

    int l = tid & 63, w = tid >> 6;   // 8 waves: o-rows w*16..+15
    int l15 = l & 15, lk = (l >> 4) * 8, rsub = (l >> 4) * 4;
    int ro = w * 16 + l15;
    int og = (tid & 31) * 4;        // 4 consecutive c-rows per thread
    int tg = tid >> 5;              // 0..15 -> 8 t-rows each

    f32x4 acc[8] = {};
    float rsum = 0.f;
#pragma unroll
    for (int c = 0; c < 2; c++) {
        int kb = ks * 256 + c * 128;
        const float* asrc = attn + ((size_t)b * NT + kb) * 128;
        const float* tsrc = tok  + ((size_t)b * NT + kb) * 128;
        if (c) __syncthreads();   // prior chunk's MFMA reads done before overwrite
        // ---- stage: fp32 [128 t][128 c] -> LDS bf16 [c][t'] swizzled ----
#pragma unroll
        for (int half = 0; half < 2; half++) {
            const float* src = half ? tsrc : asrc;
            u16* buf = half ? dT : aT;
            int t0 = tg * 8;
            f32x4 v[8];
#pragma unroll
            for (int i = 0; i < 8; i++)
                v[i] = *reinterpret_cast<const f32x4*>(src + (size_t)(t0 + i) * 128 + og);
            int gr = t0 >> 3;   // 0..15
#pragma unroll
            for (int j = 0; j < 4; j++) {
                int o = og + j;
                bf16x8 pk;
#pragma unroll
                for (int i = 0; i < 8; i++) pk[i] = (short)f2bf(v[i][j]);
                *reinterpret_cast<bf16x8*>(&buf[o * 128 + ((gr ^ (o & 15)) << 3)]) = pk;
            }
        }
        __syncthreads();
        // ---- MFMA: K = 128 for this chunk ----
#pragma unroll
        for (int kk = 0; kk < 4; kk++) {
            int tt = kk * 32 + lk;
            bf16x8 a = *reinterpret_cast<const bf16x8*>(
                &aT[ro * 128 + (((tt >> 3) ^ (ro & 15)) << 3)]);
#pragma unroll
            for (int i = 0; i < 8; i++) rsum += bf2f(a[i]);
#pragma unroll
            for (int ct = 0; ct < 8; ct++) {
                int d = ct * 16 + l15;
                bf16x8 bf = *reinterpret_cast<const bf16x8*>(
                    &dT[d * 128 + (((tt >> 3) ^ (d & 15)) << 3)]);
                acc[ct] = __builtin_amdgcn_mfma_f32_16x16x32_bf16(a, bf, acc[ct], 0, 0, 0);
            }
        }
    }
    rsum += __shfl_xor(rsum, 16, 64);
    rsum += __shfl_xor(rsum, 32, 64);
    if (l < 16) rs_part[((size_t)ks * NB + b) * NO + w * 16 + l15] = rsum;
    u16* pout = Psl + (((size_t)(ks * NB + b)) * NO + w * 16) * ND;
#pragma unroll
    for (int ct = 0; ct < 8; ct++)
#pragma unroll
        for (int r = 0; r < 4; r++)
            pout[(size_t)(rsub + r) * ND + ct * 16 + l15] = f2bf(acc[ct][r]);

    // ---- msg_o tail: only ks==0 blocks; reuse aT (WmoT) and dT (output restage) ----
    if (ks == 0) {
        __syncthreads();
        // stage Wmo^T bf16, XOR-swizzled, into aT
#pragma unroll
        for (int i = 0; i < 32; i++) {
            int idx = i * 512 + tid;
            int k = idx >> 7, n = idx & 127;
            aT[n * 128 + (k ^ ((n & 7) << 3))] = f2bf(Wmo[idx]);
        }
        __syncthreads();
        // msg = obj[b] @ Wmo + bmo  (rows o = w*16..+15, cols n = 0..127)
        f32x4 mc[8] = {};
        const float* xp = obj + ((size_t)b * NO + w * 16 + l15) * 128;
#pragma unroll
        for (int kk = 0; kk < 4; kk++) {
            bf16x8 a = frag_from_f32(xp + kk * 32 + lk);
#pragma unroll
            for (int ct = 0; ct < 8; ct++) {
                int n = ct * 16 + l15;
                bf16x8 bfr = *reinterpret_cast<const bf16x8*>(
                    &aT[n * 128 + ((kk * 32 + lk) ^ ((n & 7) << 3))]);
                mc[ct] = __builtin_amdgcn_mfma_f32_16x16x32_bf16(a, bfr, mc[ct], 0, 0, 0);
            }
        }
        // store swizzled into dT[n][o^swz]
#pragma unroll
        for (int ct = 0; ct < 8; ct++) {
            int n = ct * 16 + l15;
            float bv = bmo[n];
            ushort4 pk;
            pk.x = f2bf(mc[ct][0] + bv);
            pk.y = f2bf(mc[ct][1] + bv);
            pk.z = f2bf(mc[ct][2] + bv);
            pk.w = f2bf(mc[ct][3] + bv);
            int o = w * 16 + rsub;
            *reinterpret_cast<ushort4*>(&dT[n * 128 + (o ^ ((n & 7) << 3))]) = pk;
        }
        __syncthreads();
        // linear coalesced copy dT -> msg_oT[b] (layout preserved, stays swizzled)
        u16* mout = msg_oT + (size_t)b * 16384;
#pragma unroll
        for (int i = 0; i < 4; i++) {
            int idx2 = (i * 512 + tid) * 8;
            *reinterpret_cast<bf16x8*>(mout + idx2) = *reinterpret_cast<const bf16x8*>(&dT[idx2]);
        }
    }
}

// ---------------------------------------------------------------------------
// Obj finalize: P = sum slices; agg = P@Wmt + rowsum*bmt; new_o = LN(obj + relu([obj,agg]@Wuo + buo))
__global__ __launch_bounds__(256, 4)
void k_obj_final(const float* __restrict__ obj, const u16* __restrict__ Psl,
                 const float* __restrict__ rs_part, const u16* __restrict__ WmtT,
                 const float* __restrict__ bmt, const u16* __restrict__ WuoT,
                 const float* __restrict__ buo, const float* __restrict__ g,
                 const float* __restrict__ beta, float* __restrict__ out) {
    __shared__ u16 P_lds[32][136];
    __shared__ u16 agg_lds[32][136];
    __shared__ float rs_lds[32];
    __shared__ float part_s[32][2], part_sq[32][2];
    int bid = blockIdx.x;
    int b = bid >> 2, ot = bid & 3;
    int ob = ot * 32;
    int tid = threadIdx.x;
    {   // slice-sum -> P_lds (bf16), rowsum -> rs_lds
        int row = tid >> 3, c0 = (tid & 7) * 16;
        float sm[16];
#pragma unroll
        for (int i = 0; i < 16; i++) sm[i] = 0.f;
#pragma unroll
        for (int ks = 0; ks < 4; ks++) {
            const u16* p = Psl + (((size_t)(ks * NB + b)) * NO + ob + row) * ND + c0;
            bf16x8 v0 = *reinterpret_cast<const bf16x8*>(p);
            bf16x8 v1 = *reinterpret_cast<const bf16x8*>(p + 8);
#pragma unroll
            for (int i = 0; i < 8; i++) { sm[i] += bf2f(v0[i]); sm[8 + i] += bf2f(v1[i]); }
        }
#pragma unroll
        for (int j = 0; j < 4; j++) {
            ushort4 pk;
            pk.x = f2bf(sm[j * 4 + 0]); pk.y = f2bf(sm[j * 4 + 1]);
            pk.z = f2bf(sm[j * 4 + 2]); pk.w = f2bf(sm[j * 4 + 3]);
            *reinterpret_cast<ushort4*>(&P_lds[row][c0 + j * 4]) = pk;
        }
        if (tid < 32) {
            float r = 0.f;
#pragma unroll
            for (int ks = 0; ks < 4; ks++) r += rs_part[((size_t)ks * NB + b) * NO + ob + tid];
            rs_lds[tid] = r;
        }
    }
    __syncthreads();
    int l = tid & 63, w = tid >> 6;
    int l15 = l & 15, lk = (l >> 4) * 8, rsub = (l >> 4) * 4;
    int wr = (w & 1) * 16, wc = (w >> 1) * 64;
    // agg = P @ Wmt (K=128) + rowsum*bmt
    f32x4 agg[4] = {};
#pragma unroll
    for (int kk = 0; kk < 4; kk++) {
        bf16x8 a = *reinterpret_cast<const bf16x8*>(&P_lds[wr + l15][kk * 32 + lk]);
#pragma unroll
        for (int ct = 0; ct < 4; ct++) {
            bf16x8 bf = *reinterpret_cast<const bf16x8*>(WmtT + (wc + ct * 16 + l15) * 128 + kk * 32 + lk);
            agg[ct] = __builtin_amdgcn_mfma_f32_16x16x32_bf16(a, bf, agg[ct], 0, 0, 0);
        }
    }
#pragma unroll
    for (int ct = 0; ct < 4; ct++) {
        int n = wc + ct * 16 + l15;
        float bb = bmt[n];
#pragma unroll
        for (int r = 0; r < 4; r++) {
            float v = agg[ct][r] + rs_lds[wr + rsub + r] * bb;
            agg_lds[wr + rsub + r][n] = f2bf(v);
        }
    }
    __syncthreads();
    // MLP K=256: [obj, agg] @ WuoT
    f32x4 accm[4] = {};
    const float* objp = obj + ((size_t)(b * NO) + ob + wr + l15) * ND;
#pragma unroll
    for (int kk = 0; kk < 8; kk++) {
        int k0 = kk * 32;
        bf16x8 a = (k0 < 128) ? frag_from_f32(objp + k0 + lk)
                              : *reinterpret_cast<const bf16x8*>(&agg_lds[wr + l15][k0 - 128 + lk]);
#pragma unroll
        for (int ct = 0; ct < 4; ct++) {
            bf16x8 bf = *reinterpret_cast<const bf16x8*>(WuoT + (wc + ct * 16 + l15) * 256 + k0 + lk);
            accm[ct] = __builtin_amdgcn_mfma_f32_16x16x32_bf16(a, bf, accm[ct], 0, 0, 0);
        }
    }
    // residual + relu + LN partials (64 cols per wave)
    const float* objr = obj + ((size_t)(b * NO) + ob) * ND;
    float s[4] = {0.f, 0.f, 0.f, 0.f}, sq[4] = {0.f, 0.f, 0.f, 0.f};
#pragma unroll
    for (int ct = 0; ct < 4; ct++) {
        int n = wc + ct * 16 + l15;
        float bv = buo[n];
#pragma unroll
        for (int r = 0; r < 4; r++) {
            int lr = wr + rsub + r;
            float v = objr[(size_t)lr * ND + n] + fmaxf(accm[ct][r] + bv, 0.f);
            accm[ct][r] = v;
            s[r] += v;
            sq[r] += v * v;
        }
    }
#pragma unroll
    for (int ofs = 1; ofs < 16; ofs <<= 1) {
#pragma unroll
        for (int r = 0; r < 4; r++) {
            s[r]  += __shfl_xor(s[r], ofs, 64);
            sq[r] += __shfl_xor(sq[r], ofs, 64);
        }
    }
    if (l15 < 4) {
        float sv = (l15 == 0) ? s[0] : (l15 == 1) ? s[1] : (l15 == 2) ? s[2] : s[3];
        float qv = (l15 == 0) ? sq[0] : (l15 == 1) ? sq[1] : (l15 == 2) ? sq[2] : sq[3];
        part_s[wr + rsub + l15][w >> 1] = sv;
        part_sq[wr + rsub + l15][w >> 1] = qv;
    }
    __syncthreads();
    float mu[4], rstd[4];
#pragma unroll
    for (int r = 0; r < 4; r++) {
        int lr = wr + rsub + r;
        float st = part_s[lr][0] + part_s[lr][1];
        float qt = part_sq[lr][0] + part_sq[lr][1];
        mu[r] = st * (1.f / 128.f);
        rstd[r] = rsqrtf(qt * (1.f / 128.f) - mu[r] * mu[r] + 1e-5f);
    }
#pragma unroll
    for (int ct = 0; ct < 4; ct++) {
        int n = wc + ct * 16 + l15;
        float gn = g[n], bn = beta[n];
#pragma unroll
        for (int r = 0; r < 4; r++) {
            int lr = wr + rsub + r;
            out[((size_t)(b * NO) + ob + lr) * ND + n] = (accm[ct][r] - mu[r]) * rstd[r] * gn + bn;
        }
    }
}

// ---------------------------------------------------------------------------
// Token side (R9 best-known): grid 256, 512 thr, XCD swizzle, per-pass hoisted loads.
__global__ __launch_bounds__(512, 2)
void k_token_update(const float* __restrict__ tok, const float* __restrict__ attn,
                    const u16* __restrict__ msg_oT, const u16* __restrict__ WutT,
                    const float* __restrict__ bupd, const float* __restrict__ g,
                    const float* __restrict__ beta, float* __restrict__ out) {
    __shared__ u16 msg_lds[16384];      // 32 KB, swizzled layout
    __shared__ u16 wut_lds[32768];      // 64 KB, swizzled layout
    __shared__ u16 agg_b[8][16][136];   // per-wave agg bounce, 34 KB
    int i = blockIdx.x;
    int b  = ((i >> 5) << 3) + (i & 7);   // bijective XCD-grouping swizzle
    int bq = (i >> 3) & 3;
    int tid = threadIdx.x;
    {   // stage panels (linear copy; swizzle already baked into global layout)
        const u16* msrc = msg_oT + (size_t)b * 16384;
#pragma unroll
        for (int k = 0; k < 4; k++) {
            int idx = (k * 512 + tid) * 8;
            *reinterpret_cast<bf16x8*>(&msg_lds[idx]) = *reinterpret_cast<const bf16x8*>(msrc + idx);
        }
#pragma unroll
        for (int k = 0; k < 8; k++) {
            int idx = (k * 512 + tid) * 8;
            *reinterpret_cast<bf16x8*>(&wut_lds[idx]) = *reinterpret_cast<const bf16x8*>(WutT + idx);
        }
    }
    __syncthreads();
    int l = tid & 63, w = tid >> 6;   // 8 waves
    int l15 = l & 15, lk = (l >> 4) * 8, rsub = (l >> 4) * 4;

#pragma unroll
    for (int pass = 0; pass < 2; pass++) {
        int trow = bq * 256 + pass * 128 + w * 16;
        size_t rbase = (size_t)b * NT + trow;
        const float* aF   = attn + (rbase + l15) * NO;
        const float* tokp = tok + (rbase + l15) * ND;
        const float* tokr = tok + rbase * ND;

        // ---- hoisted global loads: attn frags, tok frags, residual ----
        bf16x8 af[4];
#pragma unroll
        for (int kk = 0; kk < 4; kk++)
            af[kk] = frag_from_f32(aF + kk * 32 + lk);
        bf16x8 am0[4];
#pragma unroll
        for (int kk = 0; kk < 4; kk++)
            am0[kk] = frag_from_f32(tokp + kk * 32 + lk);
        float resv[8][4];
#pragma unroll
        for (int ct = 0; ct < 8; ct++)
#pragma unroll
            for (int r = 0; r < 4; r++)
                resv[ct][r] = tokr[(size_t)(rsub + r) * ND + ct * 16 + l15];

        // Phase A: agg = attn @ msg_o (K=128), B from LDS.
        f32x4 acc[8] = {};
#pragma unroll
        for (int kk = 0; kk < 4; kk++) {
#pragma unroll
            for (int ct = 0; ct < 8; ct++) {
                int n = ct * 16 + l15;
                bf16x8 bf = *reinterpret_cast<const bf16x8*>(
                    &msg_lds[n * 128 + ((kk * 32 + lk) ^ ((n & 7) << 3))]);
                acc[ct] = __builtin_amdgcn_mfma_f32_16x16x32_bf16(af[kk], bf, acc[ct], 0, 0, 0);
            }
        }
        // Phase B: acc -> wave-local agg bounce (C layout -> A layout)
#pragma unroll
        for (int ct = 0; ct < 8; ct++) {
            int n = ct * 16 + l15;
#pragma unroll
            for (int r = 0; r < 4; r++)
                agg_b[w][rsub + r][n] = f2bf(acc[ct][r]);
        }
        asm volatile("s_waitcnt lgkmcnt(0)" ::: "memory");
        __builtin_amdgcn_sched_barrier(0);
        // Phase C: MLP K=256. A: tok frags (preloaded) + agg (LDS); B: wut_lds.
        bf16x8 am[8];
#pragma unroll
        for (int kk = 0; kk < 4; kk++) am[kk] = am0[kk];
#pragma unroll
        for (int kk = 0; kk < 4; kk++)
            am[4 + kk] = *reinterpret_cast<const bf16x8*>(&agg_b[w][l15][kk * 32 + lk]);
        f32x4 accm[8] = {};
#pragma unroll
        for (int kk = 0; kk < 8; kk++) {
#pragma unroll
            for (int ct = 0; ct < 8; ct++) {
                int n = ct * 16 + l15;
                bf16x8 bf = *reinterpret_cast<const bf16x8*>(
                    &wut_lds[n * 256 + ((kk * 32 + lk) ^ ((n & 7) << 3))]);
                accm[ct] = __builtin_amdgcn_mfma_f32_16x16x32_bf16(am[kk], bf, accm[ct], 0, 0, 0);
            }
        }
        // Phase D: residual + bias + relu + per-row partial sums (preloaded residual)
        float s[4] = {0.f, 0.f, 0.f, 0.f}, sq[4] = {0.f, 0.f, 0.f, 0.f};
#pragma unroll
        for (int ct = 0; ct < 8; ct++) {
            int n = ct * 16 + l15;
            float bv = bupd[n];
#pragma unroll
            for (int r = 0; r < 4; r++) {
                float v = resv[ct][r] + fmaxf(accm[ct][r] + bv, 0.f);
                accm[ct][r] = v;
                s[r] += v;
                sq[r] += v * v;
            }
        }
        // Phase E: 16-lane reduce, normalize, write
#pragma unroll
        for (int ofs = 1; ofs < 16; ofs <<= 1) {
#pragma unroll
            for (int r = 0; r < 4; r++) {
                s[r]  += __shfl_xor(s[r], ofs, 64);
                sq[r] += __shfl_xor(sq[r], ofs, 64);
            }
        }
        float mu[4], rstd[4];
#pragma unroll
        for (int r = 0; r < 4; r++) {
            mu[r] = s[r] * (1.f / 128.f);
            rstd[r] = rsqrtf(sq[r] * (1.f / 128.f) - mu[r] * mu[r] + 1e-5f);
        }
#pragma unroll
        for (int ct = 0; ct < 8; ct++) {
            int n = ct * 16 + l15;
            float gn = g[n], bn = beta[n];
#pragma unroll
            for (int r = 0; r < 4; r++)
                out[(rbase + rsub + r) * ND + n] = (accm[ct][r] - mu[r]) * rstd[r] * gn + bn;
        }
    }
}

// ---------------------------------------------------------------------------
extern "C" void kernel_launch(void* const* d_in, const int* in_sizes, int n_in,
                              void* d_out, int out_size, void* d_ws, size_t ws_size,
                              hipStream_t stream) {
    const float* tok  = (const float*)d_in[0];
    const float* obj  = (const float*)d_in[1];
    const float* attn = (const float*)d_in[2];
    const float* Wmo  = (const float*)d_in[3];
    const float* bmo  = (const float*)d_in[4];
    const float* Wmt  = (const float*)d_in[5];
    const float* bmt  = (const float*)d_in[6];
    const float* Wut  = (const float*)d_in[7];
    const float* but  = (const float*)d_in[8];
    const float* Wuo  = (const float*)d_in[9];
    const float* buo  = (const float*)d_in[10];
    const float* gt   = (const float*)d_in[11];
    const float* bt   = (const float*)d_in[12];
    const float* go   = (const float*)d_in[13];
    const float* bo   = (const float*)d_in[14];
    float* out = (float*)d_out;

    u16* ws = (u16*)d_ws;
    u16* msg_oT = ws;                        // 1048576 u16 (swizzled)
    u16* WmtT   = msg_oT + 1048576;          // 16384
    u16* WutT   = WmtT + 16384;              // 32768 (swizzled)
    u16* WuoT   = WutT + 32768;              // 32768
    u16* Psl    = WuoT + 32768;              // 4194304 (bf16 P slices [4][64][128][128])
    float* rs_part = (float*)(Psl + 4194304);// 32768 f32

    k_P<<<dim3(256), dim3(512), 0, stream>>>(attn, tok, obj, Wmo, bmo, Wmt, Wut, Wuo,
                                             Psl, rs_part, msg_oT, WmtT, WutT, WuoT);
    k_token_update<<<dim3(256), dim3(512), 0, stream>>>(tok, attn, msg_oT, WutT, but, gt, bt, out);
    k_obj_final<<<dim3(256), dim3(256), 0, stream>>>(obj, Psl, rs_part, WmtT, bmt, WuoT, buo, go, bo,
                                                     out + (size_t)NB * NT * ND);
}